// Round 2
// baseline (11038.804 us; speedup 1.0000x reference)
//
#include <hip/hip_runtime.h>

#define TSTEPS 8192
#define H 51
#define G (4 * H)   // 204 gate rows per layer
#define HP 52       // padded hidden (multiple of 4)

typedef float f4  __attribute__((ext_vector_type(4)));
typedef float v52 __attribute__((ext_vector_type(52)));  // SSA value -> guaranteed VGPRs

__device__ __forceinline__ float sigmoidf_fast(float x) {
    float t = __expf(-x);
    return __builtin_amdgcn_rcpf(1.0f + t);
}

__device__ __forceinline__ float tanhf_fast(float x) {
    x = fminf(fmaxf(x, -30.0f), 30.0f);   // avoid inf/inf -> NaN
    float t = __expf(-2.0f * x);
    return (1.0f - t) * __builtin_amdgcn_rcpf(1.0f + t);
}

// One persistent workgroup (4 waves, one CU). Thread r (r<204) owns gate-row r
// of BOTH layers, with the three 51-wide weight rows held in ext-vector VGPRs.
// Phase 1 computes z1(t) AND the h2(t-1) half of z2 (both depend only on t-1
// state); phase 3 adds the Wih2*h1(t) half. Gates are stored interleaved
// (4*unit+gate) so each cell lane reads its i,f,g,o with one ds_read_b128.
__global__ __launch_bounds__(256, 1)
void lstm2_persistent_kernel(const float* __restrict__ x,
                             const float* __restrict__ Wih1,
                             const float* __restrict__ Whh1,
                             const float* __restrict__ bih1,
                             const float* __restrict__ bhh1,
                             const float* __restrict__ Wih2,
                             const float* __restrict__ Whh2,
                             const float* __restrict__ bih2,
                             const float* __restrict__ bhh2,
                             const float* __restrict__ Wlin,
                             const float* __restrict__ blin,
                             float* __restrict__ out)
{
    __shared__ __align__(16) float sh_hh[2 * HP];  // h1 @ [0..50], h2 @ [52..102], pads zero
    __shared__ __align__(16) float sh_z1[G];       // interleaved: [4*unit + gate]
    __shared__ __align__(16) float sh_z2[G];

    const int tid = threadIdx.x;

    // ---- one-time: weight rows into register-resident vectors ----
    v52 w1, w2a, w2b;
    float b1 = 0.0f, b2 = 0.0f, wx1 = 0.0f;
    if (tid < G) {
        const int r = tid * H;
        wx1 = Wih1[tid];                 // C == 1
        b1  = bih1[tid] + bhh1[tid];
        b2  = bih2[tid] + bhh2[tid];
#pragma unroll
        for (int k = 0; k < H; ++k) {
            w1[k]  = Whh1[r + k];
            w2a[k] = Wih2[r + k];
            w2b[k] = Whh2[r + k];
        }
        w1[51] = 0.0f; w2a[51] = 0.0f; w2b[51] = 0.0f;  // pad lane
    }
    const float wlin = (tid < H) ? Wlin[tid] : 0.0f;
    const float bl   = blin[0];
    const int zslot  = (tid < G) ? ((tid % H) * 4 + (tid / H)) : 0;  // gate-interleaved slot

    float c1 = 0.0f, c2 = 0.0f;
    if (tid < 2 * HP) sh_hh[tid] = 0.0f;   // includes the two pad slots
    __syncthreads();

    const f4* hv1 = (const f4*)sh_hh;         // 13 chunks of h1 (+pad)
    const f4* hv2 = (const f4*)(sh_hh + HP);  // 13 chunks of h2 (+pad)

    float x_t = x[0];
    float u[4];  // partial z2 accumulators, carried phase1 -> phase3

    for (int t = 0; t < TSTEPS; ++t) {
        const float xn = x[(t + 1) & (TSTEPS - 1)];  // prefetch (wraps harmlessly)

        // ---- phase 1: z1 = b1 + x*wx1 + Whh1.h1(t-1);  u2 = b2 + Whh2.h2(t-1) ----
        if (tid < G) {
            float a[4];
            a[0] = fmaf(x_t, wx1, b1); a[1] = 0.0f; a[2] = 0.0f; a[3] = 0.0f;
            u[0] = b2;                 u[1] = 0.0f; u[2] = 0.0f; u[3] = 0.0f;
#pragma unroll
            for (int p = 0; p < 13; ++p) {
                const f4 hc = hv1[p];
                const f4 gc = hv2[p];
#pragma unroll
                for (int j = 0; j < 4; ++j) {
                    a[j] = fmaf(w1[4 * p + j],  hc[j], a[j]);
                    u[j] = fmaf(w2b[4 * p + j], gc[j], u[j]);
                }
            }
            sh_z1[zslot] = (a[0] + a[1]) + (a[2] + a[3]);
        }
        x_t = xn;
        __syncthreads();

        // ---- phase 2: cell-1 update (lanes 0..50 of wave 0) ----
        if (tid < H) {
            const f4 zi = ((const f4*)sh_z1)[tid];   // i,f,g,o in one b128
            const float ig = sigmoidf_fast(zi[0]);
            const float fg = sigmoidf_fast(zi[1]);
            const float gg = tanhf_fast(zi[2]);
            const float og = sigmoidf_fast(zi[3]);
            c1 = fmaf(fg, c1, ig * gg);
            sh_hh[tid] = og * tanhf_fast(c1);
        }
        __syncthreads();

        // ---- phase 3: z2 = u2 + Wih2.h1(t) ----
        if (tid < G) {
#pragma unroll
            for (int p = 0; p < 13; ++p) {
                const f4 hc = hv1[p];
#pragma unroll
                for (int j = 0; j < 4; ++j)
                    u[j] = fmaf(w2a[4 * p + j], hc[j], u[j]);
            }
            sh_z2[zslot] = (u[0] + u[1]) + (u[2] + u[3]);
        }
        __syncthreads();

        // ---- phase 4: cell-2 update + output dot (wave 0) ----
        float h2v = 0.0f;
        if (tid < H) {
            const f4 zi = ((const f4*)sh_z2)[tid];
            const float ig = sigmoidf_fast(zi[0]);
            const float fg = sigmoidf_fast(zi[1]);
            const float gg = tanhf_fast(zi[2]);
            const float og = sigmoidf_fast(zi[3]);
            c2 = fmaf(fg, c2, ig * gg);
            h2v = og * tanhf_fast(c2);
            sh_hh[HP + tid] = h2v;
        }
        if (tid < 64) {  // wave 0: out[t] = h2 . Wlin + blin
            float p = h2v * wlin;
            p += __shfl_down(p, 32);
            p += __shfl_down(p, 16);
            p += __shfl_down(p, 8);
            p += __shfl_down(p, 4);
            p += __shfl_down(p, 2);
            p += __shfl_down(p, 1);
            if (tid == 0) out[t] = p + bl;
        }
        __syncthreads();
    }
}

extern "C" void kernel_launch(void* const* d_in, const int* in_sizes, int n_in,
                              void* d_out, int out_size, void* d_ws, size_t ws_size,
                              hipStream_t stream) {
    const float* x    = (const float*)d_in[0];
    const float* Wih1 = (const float*)d_in[1];
    const float* Whh1 = (const float*)d_in[2];
    const float* bih1 = (const float*)d_in[3];
    const float* bhh1 = (const float*)d_in[4];
    const float* Wih2 = (const float*)d_in[5];
    const float* Whh2 = (const float*)d_in[6];
    const float* bih2 = (const float*)d_in[7];
    const float* bhh2 = (const float*)d_in[8];
    const float* Wlin = (const float*)d_in[9];
    const float* blin = (const float*)d_in[10];
    float* out = (float*)d_out;

    lstm2_persistent_kernel<<<1, 256, 0, stream>>>(
        x, Wih1, Whh1, bih1, bhh1, Wih2, Whh2, bih2, bhh2, Wlin, blin, out);
}

// Round 3
// 10591.979 us; speedup vs baseline: 1.0422x; 1.0422x over previous
//
#include <hip/hip_runtime.h>

#define TSTEPS 8192
#define H 51
#define G 204   // 4*H gate rows per layer

typedef float f4  __attribute__((ext_vector_type(4)));
typedef float v52 __attribute__((ext_vector_type(52)));

__device__ __forceinline__ float rlane(float v, int k) {
    return __int_as_float(__builtin_amdgcn_readlane(__float_as_int(v), k));
}
__device__ __forceinline__ float sigmoidf_fast(float x) {
    return __builtin_amdgcn_rcpf(1.0f + __expf(-x));
}
__device__ __forceinline__ float tanhf_fast(float x) {
    x = fminf(fmaxf(x, -15.0f), 15.0f);
    float t = __expf(-2.0f * x);
    return (1.0f - t) * __builtin_amdgcn_rcpf(1.0f + t);
}

// One persistent workgroup: 4 waves, 1 per SIMD. Lane r (<204) owns gate-row r
// of both layers, weights register-resident (amdgpu_waves_per_eu(1,1) sets the
// allocator budget to ~512 VGPR so the ~156 weight regs stay live instead of
// being re-fetched from global every step — R1/R2's 100 MB FETCH_SIZE bug).
// h1/h2 live replicated in each wave's lanes 0..50; dot products broadcast h
// via v_readlane (SGPR operand of v_fmac) — no LDS broadcast traffic.
// Row-lanes apply gate activations before storing to LDS, so the replicated
// cell update is just c=f*c+i*g; h=o*tanh(c). Two barriers per step.
__global__ __attribute__((amdgpu_waves_per_eu(1, 1))) __launch_bounds__(256)
void lstm2_persistent_kernel(const float* __restrict__ x,
                             const float* __restrict__ Wih1,
                             const float* __restrict__ Whh1,
                             const float* __restrict__ bih1,
                             const float* __restrict__ bhh1,
                             const float* __restrict__ Wih2,
                             const float* __restrict__ Whh2,
                             const float* __restrict__ bih2,
                             const float* __restrict__ bhh2,
                             const float* __restrict__ Wlin,
                             const float* __restrict__ blin,
                             float* __restrict__ out)
{
    __shared__ __align__(16) float sh_a1[256];  // activated gates L1, [unit*4+gate]
    __shared__ __align__(16) float sh_a2[256];  // activated gates L2

    const int tid  = threadIdx.x;
    const int lane = tid & 63;
    const int row  = (tid < G) ? tid : (G - 1);  // clamp: lanes 204..255 duplicate row 203
    const int gate = row / H;                    // 0=i,1=f,2=g,3=o (PyTorch order)
    const int unit = row - gate * H;

    // branchless activation: gate g uses tanh(z) = 2*sigmoid(2z) - 1
    const float sA = (gate == 2) ? 2.0f : 1.0f;
    const float mA = (gate == 2) ? 2.0f : 1.0f;
    const float cA = (gate == 2) ? -1.0f : 0.0f;

    // ---- one-time: register-resident weight rows ----
    v52 w1, w2a, w2b;
    {
        const float* p1 = Whh1 + row * H;
        const float* p2 = Wih2 + row * H;
        const float* p3 = Whh2 + row * H;
#pragma unroll
        for (int k = 0; k < H; ++k) { w1[k] = p1[k]; w2a[k] = p2[k]; w2b[k] = p3[k]; }
        w1[51] = 0.0f; w2a[51] = 0.0f; w2b[51] = 0.0f;
    }
    const float wx1  = Wih1[row];                 // C == 1
    const float b1   = bih1[row] + bhh1[row];
    const float b2   = bih2[row] + bhh2[row];
    const float wlin = (lane < H) ? Wlin[lane] : 0.0f;
    const float bl   = blin[0];
    const int zslot  = unit * 4 + gate;

    float hv1 = 0.0f, hv2 = 0.0f, c1 = 0.0f, c2 = 0.0f;
    sh_a1[tid] = 0.0f; sh_a2[tid] = 0.0f;
    __syncthreads();

    float x_t = x[0];

#pragma unroll 1
    for (int t = 0; t < TSTEPS; ++t) {
        const float xn = x[(t + 1) & (TSTEPS - 1)];  // prefetch, wraps harmlessly

        // ---- phase A: z1 row (needs h1(t-1)) + Whh2.h2(t-1) half of z2 ----
        float a  = fmaf(x_t, wx1, b1);
        float u2 = b2;
#pragma unroll
        for (int k = 0; k < H; ++k) {
            a  = fmaf(w1[k],  rlane(hv1, k), a);
            u2 = fmaf(w2b[k], rlane(hv2, k), u2);
        }
        const float act1 = fmaf(mA, sigmoidf_fast(sA * a), cA);
        if (tid < G) sh_a1[zslot] = act1;
        x_t = xn;
        __syncthreads();

        // ---- cell 1 (replicated per wave; lanes 0..50 meaningful) ----
        {
            const f4 gv = ((const f4*)sh_a1)[lane];   // i,f,g,o activated
            c1 = fmaf(gv[1], c1, gv[0] * gv[2]);
            const float h1n = gv[3] * tanhf_fast(c1);
            hv1 = (lane < H) ? h1n : 0.0f;
        }

        // ---- phase B: z2 += Wih2.h1(t) ----
#pragma unroll
        for (int k = 0; k < H; ++k)
            u2 = fmaf(w2a[k], rlane(hv1, k), u2);
        const float act2 = fmaf(mA, sigmoidf_fast(sA * u2), cA);
        if (tid < G) sh_a2[zslot] = act2;
        __syncthreads();

        // ---- cell 2 (replicated) + output dot (wave 0) ----
        {
            const f4 gv = ((const f4*)sh_a2)[lane];
            c2 = fmaf(gv[1], c2, gv[0] * gv[2]);
            const float h2n = gv[3] * tanhf_fast(c2);
            hv2 = (lane < H) ? h2n : 0.0f;
        }
        if (tid < 64) {
            float p = hv2 * wlin;
            p += __shfl_down(p, 32);
            p += __shfl_down(p, 16);
            p += __shfl_down(p, 8);
            p += __shfl_down(p, 4);
            p += __shfl_down(p, 2);
            p += __shfl_down(p, 1);
            if (tid == 0) out[t] = p + bl;
        }
    }
}

extern "C" void kernel_launch(void* const* d_in, const int* in_sizes, int n_in,
                              void* d_out, int out_size, void* d_ws, size_t ws_size,
                              hipStream_t stream) {
    const float* x    = (const float*)d_in[0];
    const float* Wih1 = (const float*)d_in[1];
    const float* Whh1 = (const float*)d_in[2];
    const float* bih1 = (const float*)d_in[3];
    const float* bhh1 = (const float*)d_in[4];
    const float* Wih2 = (const float*)d_in[5];
    const float* Whh2 = (const float*)d_in[6];
    const float* bih2 = (const float*)d_in[7];
    const float* bhh2 = (const float*)d_in[8];
    const float* Wlin = (const float*)d_in[9];
    const float* blin = (const float*)d_in[10];
    float* out = (float*)d_out;

    lstm2_persistent_kernel<<<1, 256, 0, stream>>>(
        x, Wih1, Whh1, bih1, bhh1, Wih2, Whh2, bih2, bhh2, Wlin, blin, out);
}

// Round 4
// 10556.103 us; speedup vs baseline: 1.0457x; 1.0034x over previous
//
#include <hip/hip_runtime.h>

#define TSTEPS 8192
#define H 51
#define G 204     // 4*H gate rows per layer
#define HP 52     // padded hidden (13 f4 chunks)
#define NW 12     // waves
#define NT 768    // threads

typedef float f4  __attribute__((ext_vector_type(4)));
typedef float v52 __attribute__((ext_vector_type(52)));

__device__ __forceinline__ float sigmoidf_fast(float x) {
    return __builtin_amdgcn_rcpf(1.0f + __expf(-x));
}
__device__ __forceinline__ float tanhf_fast(float x) {
    x = fminf(fmaxf(x, -15.0f), 15.0f);
    float t = __expf(-2.0f * x);
    return (1.0f - t) * __builtin_amdgcn_rcpf(1.0f + t);
}

// One persistent 768-thread workgroup (12 waves, 3/SIMD). Weight matrices are
// split across wave-groups so each thread holds ONE 52-float row (~85 VGPRs,
// far under the 170 cap at 3 waves/EU -> no spill/remat, unlike R1-R3 where
// 156 floats/thread kept being re-fetched from global: FETCH_SIZE 100 MB).
//   group A (waves 0-3):  Whh1 rows -> z1(t)           [critical path]
//   group B (waves 4-7):  Whh2 rows -> u2 half of z2   [concurrent with A]
//   group C (waves 8-11): Wih2 rows -> z2 = u2 + ...   [after cell-1]
// h1/h2 live in per-wave private LDS copies, read as broadcast ds_read_b128.
// Row lanes apply gate activations; cell updates replicated only where the
// result is consumed (cell-1: A,C; cell-2: B + wave 0). 2 barriers/step.
__global__ __launch_bounds__(NT) __attribute__((amdgpu_waves_per_eu(3, 3)))
void lstm2_persistent_kernel(const float* __restrict__ x,
                             const float* __restrict__ Wih1,
                             const float* __restrict__ Whh1,
                             const float* __restrict__ bih1,
                             const float* __restrict__ bhh1,
                             const float* __restrict__ Wih2,
                             const float* __restrict__ Whh2,
                             const float* __restrict__ bih2,
                             const float* __restrict__ bhh2,
                             const float* __restrict__ Wlin,
                             const float* __restrict__ blin,
                             float* __restrict__ out)
{
    __shared__ __align__(16) float sh_h1[NW][HP];  // per-wave private h1 copy
    __shared__ __align__(16) float sh_h2[NW][HP];  // per-wave private h2 copy
    __shared__ __align__(16) float sh_a1[256];     // activated L1 gates [unit*4+gate]
    __shared__ __align__(16) float sh_a2[256];     // activated L2 gates
    __shared__ __align__(16) float sh_u2[G];       // raw u2 = b2 + Whh2.h2(t-1)

    const int tid  = threadIdx.x;
    const int wave = tid >> 6;
    const int lane = tid & 63;
    const int grp  = wave >> 2;           // 0:A(Whh1) 1:B(Whh2) 2:C(Wih2)
    const int gtid = tid & 255;           // index within group
    const bool rowOwner = (gtid < G);
    const int row  = rowOwner ? gtid : (G - 1);
    const int gate = row / H;             // 0=i,1=f,2=g,3=o
    const int unit = row - gate * H;
    const int zslot = unit * 4 + gate;
    // branchless activation: g-gate uses tanh(z) = 2*sigmoid(2z) - 1
    const float sA = (gate == 2) ? 2.0f : 1.0f;
    const float mA = sA;
    const float cA = (gate == 2) ? -1.0f : 0.0f;

    // ---- one-time: one register-resident weight row per thread ----
    const float* Wmat = (grp == 0) ? Whh1 : (grp == 1) ? Whh2 : Wih2;
    v52 w;
#pragma unroll
    for (int k = 0; k < H; ++k) w[k] = Wmat[row * H + k];
    w[51] = 0.0f;
    float bias = 0.0f, wx1 = 0.0f;
    if (grp == 0) { wx1 = Wih1[row]; bias = bih1[row] + bhh1[row]; }
    if (grp == 1) { bias = bih2[row] + bhh2[row]; }

    const float wlin = (lane < H) ? Wlin[lane] : 0.0f;
    const float bl   = blin[0];

    // ---- init LDS (incl. pads and the never-rewritten a-slots 204..255) ----
    for (int i = tid; i < NW * HP; i += NT) {
        (&sh_h1[0][0])[i] = 0.0f;
        (&sh_h2[0][0])[i] = 0.0f;
    }
    if (tid < 256) { sh_a1[tid] = 0.0f; sh_a2[tid] = 0.0f; }
    if (tid < G)   sh_u2[tid] = 0.0f;
    float c1 = 0.0f, c2 = 0.0f;
    __syncthreads();

    const f4* h1v = (const f4*)sh_h1[wave];
    const f4* h2v = (const f4*)sh_h2[wave];

    float x_t = x[0];

#pragma unroll 1
    for (int t = 0; t < TSTEPS; ++t) {
        const float xn = x[(t + 1) & (TSTEPS - 1)];  // prefetch, wraps harmlessly

        // ---- phase 1: A computes z1(t); B computes u2 (both from t-1 state) ----
        if (grp == 0) {
            float a0 = fmaf(x_t, wx1, bias), a1 = 0.0f, a2 = 0.0f, a3 = 0.0f;
#pragma unroll
            for (int p = 0; p < 13; ++p) {
                const f4 hc = h1v[p];                // broadcast read, own copy
                a0 = fmaf(w[4*p+0], hc[0], a0);
                a1 = fmaf(w[4*p+1], hc[1], a1);
                a2 = fmaf(w[4*p+2], hc[2], a2);
                a3 = fmaf(w[4*p+3], hc[3], a3);
            }
            const float z   = (a0 + a1) + (a2 + a3);
            const float act = fmaf(mA, sigmoidf_fast(sA * z), cA);
            if (rowOwner) sh_a1[zslot] = act;
        } else if (grp == 1) {
            float a0 = bias, a1 = 0.0f, a2 = 0.0f, a3 = 0.0f;
#pragma unroll
            for (int p = 0; p < 13; ++p) {
                const f4 hc = h2v[p];
                a0 = fmaf(w[4*p+0], hc[0], a0);
                a1 = fmaf(w[4*p+1], hc[1], a1);
                a2 = fmaf(w[4*p+2], hc[2], a2);
                a3 = fmaf(w[4*p+3], hc[3], a3);
            }
            if (rowOwner) sh_u2[row] = (a0 + a1) + (a2 + a3);
        }
        x_t = xn;
        __syncthreads();   // publishes sh_a1, sh_u2

        // ---- phase 2: cell-1 update, replicated in h1-consumers (A, C) ----
        if (grp != 1) {
            const f4 gv = ((const f4*)sh_a1)[lane];  // lanes>=51 read zeros
            c1 = fmaf(gv[1], c1, gv[0] * gv[2]);
            const float h1n = gv[3] * tanhf_fast(c1);
            if (lane < H) sh_h1[wave][lane] = h1n;   // own private copy
        }

        // ---- phase 3: C computes z2 = u2 + Wih2.h1(t) ----
        if (grp == 2) {
            float a0 = sh_u2[row], a1 = 0.0f, a2 = 0.0f, a3 = 0.0f;
#pragma unroll
            for (int p = 0; p < 13; ++p) {
                const f4 hc = h1v[p];                // own fresh copy (lgkmcnt)
                a0 = fmaf(w[4*p+0], hc[0], a0);
                a1 = fmaf(w[4*p+1], hc[1], a1);
                a2 = fmaf(w[4*p+2], hc[2], a2);
                a3 = fmaf(w[4*p+3], hc[3], a3);
            }
            const float z   = (a0 + a1) + (a2 + a3);
            const float act = fmaf(mA, sigmoidf_fast(sA * z), cA);
            if (rowOwner) sh_a2[zslot] = act;
        }
        __syncthreads();   // publishes sh_a2

        // ---- phase 4: cell-2 in h2-consumers (B) + wave 0 (output dot) ----
        if (grp == 1 || wave == 0) {
            const f4 gv = ((const f4*)sh_a2)[lane];
            c2 = fmaf(gv[1], c2, gv[0] * gv[2]);
            const float h2n = gv[3] * tanhf_fast(c2);
            if (grp == 1 && lane < H) sh_h2[wave][lane] = h2n;
            if (wave == 0) {
                float p = h2n * wlin;                // lanes>=51: h2n==0
                p += __shfl_down(p, 32);
                p += __shfl_down(p, 16);
                p += __shfl_down(p, 8);
                p += __shfl_down(p, 4);
                p += __shfl_down(p, 2);
                p += __shfl_down(p, 1);
                if (lane == 0) out[t] = p + bl;
            }
        }
    }
}

extern "C" void kernel_launch(void* const* d_in, const int* in_sizes, int n_in,
                              void* d_out, int out_size, void* d_ws, size_t ws_size,
                              hipStream_t stream) {
    const float* x    = (const float*)d_in[0];
    const float* Wih1 = (const float*)d_in[1];
    const float* Whh1 = (const float*)d_in[2];
    const float* bih1 = (const float*)d_in[3];
    const float* bhh1 = (const float*)d_in[4];
    const float* Wih2 = (const float*)d_in[5];
    const float* Whh2 = (const float*)d_in[6];
    const float* bih2 = (const float*)d_in[7];
    const float* bhh2 = (const float*)d_in[8];
    const float* Wlin = (const float*)d_in[9];
    const float* blin = (const float*)d_in[10];
    float* out = (float*)d_out;

    lstm2_persistent_kernel<<<1, NT, 0, stream>>>(
        x, Wih1, Whh1, bih1, bhh1, Wih2, Whh2, bih2, bhh2, Wlin, blin, out);
}

// Round 5
// 10400.748 us; speedup vs baseline: 1.0613x; 1.0149x over previous
//
#include <hip/hip_runtime.h>

#define TSTEPS 8192
#define H 51
#define G 204     // 4*H gate rows per layer
#define HP 52     // padded hidden (13 f4 chunks)
#define NW 12     // waves
#define NT 768    // threads

typedef float f4  __attribute__((ext_vector_type(4)));
typedef float v52 __attribute__((ext_vector_type(52)));

__device__ __forceinline__ float sigmoidf_fast(float x) {
    return __builtin_amdgcn_rcpf(1.0f + __expf(-x));
}
__device__ __forceinline__ float tanhf_fast(float x) {
    x = fminf(fmaxf(x, -15.0f), 15.0f);
    float t = __expf(-2.0f * x);
    return (1.0f - t) * __builtin_amdgcn_rcpf(1.0f + t);
}

// One persistent 768-thread workgroup (12 waves, 3/SIMD), weight rows
// register-resident (one v52/thread, VGPR=84 — verified R4).
// R5 change: NO global memory ops inside the 8192-step loop. x is staged to
// LDS up front; out accumulates in LDS and is bulk-stored at the end. R1-R4
// all timed ~10.6 ms with wildly different math because every step paid the
// s_waitcnt vmcnt(0) drain (global load + store-ack) before each s_barrier.
//   group A (waves 0-3):  Whh1 rows -> z1(t)           [critical path]
//   group B (waves 4-7):  Whh2 rows -> u2 half of z2   [concurrent with A]
//   group C (waves 8-11): Wih2 rows -> z2 = u2 + ...   [after cell-1]
// h1/h2 in per-wave private LDS copies (broadcast ds_read_b128, no barrier
// needed between a wave's own write and read). 2 barriers/step.
__global__ __launch_bounds__(NT) __attribute__((amdgpu_waves_per_eu(3, 3)))
void lstm2_persistent_kernel(const float* __restrict__ x,
                             const float* __restrict__ Wih1,
                             const float* __restrict__ Whh1,
                             const float* __restrict__ bih1,
                             const float* __restrict__ bhh1,
                             const float* __restrict__ Wih2,
                             const float* __restrict__ Whh2,
                             const float* __restrict__ bih2,
                             const float* __restrict__ bhh2,
                             const float* __restrict__ Wlin,
                             const float* __restrict__ blin,
                             float* __restrict__ out)
{
    __shared__ __align__(16) float sh_x[TSTEPS];    // staged input (32 KB)
    __shared__ __align__(16) float sh_out[TSTEPS];  // staged output (32 KB)
    __shared__ __align__(16) float sh_h1[NW][HP];   // per-wave private h1
    __shared__ __align__(16) float sh_h2[NW][HP];   // per-wave private h2
    __shared__ __align__(16) float sh_a1[256];      // activated L1 gates [unit*4+gate]
    __shared__ __align__(16) float sh_a2[256];      // activated L2 gates
    __shared__ __align__(16) float sh_u2[G];        // u2 = b2 + Whh2.h2(t-1)

    const int tid  = threadIdx.x;
    const int wave = tid >> 6;
    const int lane = tid & 63;
    const int grp  = wave >> 2;           // 0:A(Whh1) 1:B(Whh2) 2:C(Wih2)
    const int gtid = tid & 255;
    const bool rowOwner = (gtid < G);
    const int row  = rowOwner ? gtid : (G - 1);
    const int gate = row / H;             // 0=i,1=f,2=g,3=o
    const int unit = row - gate * H;
    const int zslot = unit * 4 + gate;
    // branchless activation: g-gate uses tanh(z) = 2*sigmoid(2z) - 1
    const float sA = (gate == 2) ? 2.0f : 1.0f;
    const float mA = sA;
    const float cA = (gate == 2) ? -1.0f : 0.0f;

    // ---- one-time: stage x to LDS (coalesced f4) ----
    for (int i = tid; i < TSTEPS / 4; i += NT)
        ((f4*)sh_x)[i] = ((const f4*)x)[i];

    // ---- one-time: one register-resident weight row per thread ----
    const float* Wmat = (grp == 0) ? Whh1 : (grp == 1) ? Whh2 : Wih2;
    v52 w;
#pragma unroll
    for (int k = 0; k < H; ++k) w[k] = Wmat[row * H + k];
    w[51] = 0.0f;
    float bias = 0.0f, wx1 = 0.0f;
    if (grp == 0) { wx1 = Wih1[row]; bias = bih1[row] + bhh1[row]; }
    if (grp == 1) { bias = bih2[row] + bhh2[row]; }

    const float wlin = (lane < H) ? Wlin[lane] : 0.0f;
    const float bl   = blin[0];

    // ---- init LDS state (incl. pads and a-slots 204..255, never rewritten) ----
    for (int i = tid; i < NW * HP; i += NT) {
        (&sh_h1[0][0])[i] = 0.0f;
        (&sh_h2[0][0])[i] = 0.0f;
    }
    if (tid < 256) { sh_a1[tid] = 0.0f; sh_a2[tid] = 0.0f; }
    if (tid < G)   sh_u2[tid] = 0.0f;
    float c1 = 0.0f, c2 = 0.0f;
    __syncthreads();

    const f4* h1v = (const f4*)sh_h1[wave];
    const f4* h2v = (const f4*)sh_h2[wave];

#pragma unroll 1
    for (int t = 0; t < TSTEPS; ++t) {
        // ---- phase 1: A computes z1(t); B computes u2 (both from t-1 state) ----
        if (grp == 0) {
            const float xv = sh_x[t];                // broadcast LDS read
            float a0 = fmaf(xv, wx1, bias), a1 = 0.0f, a2 = 0.0f, a3 = 0.0f;
#pragma unroll
            for (int p = 0; p < 13; ++p) {
                const f4 hc = h1v[p];
                a0 = fmaf(w[4*p+0], hc[0], a0);
                a1 = fmaf(w[4*p+1], hc[1], a1);
                a2 = fmaf(w[4*p+2], hc[2], a2);
                a3 = fmaf(w[4*p+3], hc[3], a3);
            }
            const float z   = (a0 + a1) + (a2 + a3);
            const float act = fmaf(mA, sigmoidf_fast(sA * z), cA);
            if (rowOwner) sh_a1[zslot] = act;
        } else if (grp == 1) {
            float a0 = bias, a1 = 0.0f, a2 = 0.0f, a3 = 0.0f;
#pragma unroll
            for (int p = 0; p < 13; ++p) {
                const f4 hc = h2v[p];
                a0 = fmaf(w[4*p+0], hc[0], a0);
                a1 = fmaf(w[4*p+1], hc[1], a1);
                a2 = fmaf(w[4*p+2], hc[2], a2);
                a3 = fmaf(w[4*p+3], hc[3], a3);
            }
            if (rowOwner) sh_u2[row] = (a0 + a1) + (a2 + a3);
        }
        __syncthreads();   // publishes sh_a1, sh_u2

        // ---- phase 2: cell-1 update, replicated in h1-consumers (A, C) ----
        if (grp != 1) {
            const f4 gv = ((const f4*)sh_a1)[lane];  // lanes>=51 read zeros
            c1 = fmaf(gv[1], c1, gv[0] * gv[2]);
            const float h1n = gv[3] * tanhf_fast(c1);
            if (lane < H) sh_h1[wave][lane] = h1n;   // own private copy
        }

        // ---- phase 3: C computes z2 = u2 + Wih2.h1(t) ----
        if (grp == 2) {
            float a0 = sh_u2[row], a1 = 0.0f, a2 = 0.0f, a3 = 0.0f;
#pragma unroll
            for (int p = 0; p < 13; ++p) {
                const f4 hc = h1v[p];                // own fresh copy
                a0 = fmaf(w[4*p+0], hc[0], a0);
                a1 = fmaf(w[4*p+1], hc[1], a1);
                a2 = fmaf(w[4*p+2], hc[2], a2);
                a3 = fmaf(w[4*p+3], hc[3], a3);
            }
            const float z   = (a0 + a1) + (a2 + a3);
            const float act = fmaf(mA, sigmoidf_fast(sA * z), cA);
            if (rowOwner) sh_a2[zslot] = act;
        }
        __syncthreads();   // publishes sh_a2

        // ---- phase 4: cell-2 in h2-consumers (B) + wave 0 (output dot) ----
        if (grp == 1 || wave == 0) {
            const f4 gv = ((const f4*)sh_a2)[lane];
            c2 = fmaf(gv[1], c2, gv[0] * gv[2]);
            const float h2n = gv[3] * tanhf_fast(c2);
            if (grp == 1 && lane < H) sh_h2[wave][lane] = h2n;
            if (wave == 0) {
                float p = h2n * wlin;                // lanes>=51: h2n==0
                p += __shfl_down(p, 32);
                p += __shfl_down(p, 16);
                p += __shfl_down(p, 8);
                p += __shfl_down(p, 4);
                p += __shfl_down(p, 2);
                p += __shfl_down(p, 1);
                if (lane == 0) sh_out[t] = p + bl;   // LDS, not global
            }
        }
    }

    // ---- bulk coalesced output store ----
    __syncthreads();
    for (int i = tid; i < TSTEPS / 4; i += NT)
        ((f4*)out)[i] = ((const f4*)sh_out)[i];
}

extern "C" void kernel_launch(void* const* d_in, const int* in_sizes, int n_in,
                              void* d_out, int out_size, void* d_ws, size_t ws_size,
                              hipStream_t stream) {
    const float* x    = (const float*)d_in[0];
    const float* Wih1 = (const float*)d_in[1];
    const float* Whh1 = (const float*)d_in[2];
    const float* bih1 = (const float*)d_in[3];
    const float* bhh1 = (const float*)d_in[4];
    const float* Wih2 = (const float*)d_in[5];
    const float* Whh2 = (const float*)d_in[6];
    const float* bih2 = (const float*)d_in[7];
    const float* bhh2 = (const float*)d_in[8];
    const float* Wlin = (const float*)d_in[9];
    const float* blin = (const float*)d_in[10];
    float* out = (float*)d_out;

    lstm2_persistent_kernel<<<1, NT, 0, stream>>>(
        x, Wih1, Whh1, bih1, bhh1, Wih2, Whh2, bih2, bhh2, Wlin, blin, out);
}

// Round 6
// 5312.769 us; speedup vs baseline: 2.0778x; 1.9577x over previous
//
#include <hip/hip_runtime.h>

#define TSTEPS 8192
#define H 51

typedef float f4  __attribute__((ext_vector_type(4)));
typedef float v52 __attribute__((ext_vector_type(52)));

__device__ __forceinline__ float rlane(float v, int k) {
    return __int_as_float(__builtin_amdgcn_readlane(__float_as_int(v), k));
}
__device__ __forceinline__ float sigmoidf_fast(float x) {
    return __builtin_amdgcn_rcpf(1.0f + __expf(-x));
}
__device__ __forceinline__ float tanhf_fast(float x) {
    x = fminf(fmaxf(x, -15.0f), 15.0f);
    float t = __expf(-2.0f * x);
    return (1.0f - t) * __builtin_amdgcn_rcpf(1.0f + t);
}

// R6: wave-specialized software pipeline, column weight layout.
// R1-R5 all ~10.4ms despite wildly different math: the shared per-step
// dependency DAG (6 LDS hops + 2 barriers + in-path shuffle reduce) is the
// bottleneck, not issue count / globals / residency. This kernel cuts DAG
// depth: each wave owns one matrix in COLUMN layout (z[gate] in-lane at
// lane=unit), so activations+cell updates are lane-local, h self-loops stay
// in-wave (readlane broadcast ~5cyc, not 120cyc LDS), and the output reduce
// runs on wave3 fully off the critical path. 1 barrier/epoch, double-
// buffered LDS, 3-deep pipeline (epochs e=0..T+2):
//   wave0 @e:  h1(e)    = cell1(Whh1.h1(e-1) + x[e])        [in-wave]
//   wave2 @e:  z2a(e-1) = Wih2.h1(e-1)                       [1 LDS hop]
//   wave1 @e:  h2(e-2)  = cell2(u2(e-2) + z2a(e-2));  u2(e-1)= b2+Whh2.h2(e-2)
//   wave3 @e:  out(e-3) = Wlin.h2(e-3) + blin                [shuffle reduce]
__global__ __launch_bounds__(256) __attribute__((amdgpu_waves_per_eu(1, 1)))
void lstm2_pipe_kernel(const float* __restrict__ x,
                       const float* __restrict__ Wih1,
                       const float* __restrict__ Whh1,
                       const float* __restrict__ bih1,
                       const float* __restrict__ bhh1,
                       const float* __restrict__ Wih2,
                       const float* __restrict__ Whh2,
                       const float* __restrict__ bih2,
                       const float* __restrict__ bhh2,
                       const float* __restrict__ Wlin,
                       const float* __restrict__ blin,
                       float* __restrict__ out)
{
    __shared__ __align__(16) float sh_x[TSTEPS];     // staged input
    __shared__ __align__(16) float sh_out[TSTEPS];   // staged output
    __shared__ __align__(16) float sh_h1[2][64];     // double-buffered h1
    __shared__ __align__(16) float sh_h2[2][64];     // double-buffered h2
    __shared__ __align__(16) f4    sh_z2a[2][64];    // double-buffered z2a (4 gates/lane)

    const int tid  = threadIdx.x;
    const int wave = tid >> 6;
    const int lane = tid & 63;
    const int row  = (lane < H) ? lane : (H - 1);    // clamp for weight loads

    // ---- stage x to LDS (coalesced f4) ----
    for (int i = tid; i < TSTEPS / 4; i += 256)
        ((f4*)sh_x)[i] = ((const f4*)x)[i];

    // ---- init LDS state ----
    if (tid < 64) {
        sh_h1[0][tid] = 0.0f; sh_h1[1][tid] = 0.0f;
        sh_h2[0][tid] = 0.0f; sh_h2[1][tid] = 0.0f;
        sh_z2a[0][tid] = (f4)0.0f; sh_z2a[1][tid] = (f4)0.0f;
    }

    // ---- per-wave weight columns, volatile-pinned (cannot be sunk/remat) ----
    // wave0: Whh1, wave1: Whh2, wave2: Wih2, wave3: none
    v52 wg0, wg1, wg2, wg3;
    f4 bias = (f4)0.0f, wxv = (f4)0.0f;
    if (wave < 3) {
        const float* M = (wave == 0) ? Whh1 : (wave == 1) ? Whh2 : Wih2;
        const volatile float* vM = M;
#pragma unroll
        for (int k = 0; k < H; ++k) {
            wg0[k] = vM[(0 * H + row) * H + k];
            wg1[k] = vM[(1 * H + row) * H + k];
            wg2[k] = vM[(2 * H + row) * H + k];
            wg3[k] = vM[(3 * H + row) * H + k];
        }
        wg0[51] = 0.0f; wg1[51] = 0.0f; wg2[51] = 0.0f; wg3[51] = 0.0f;
    }
    if (wave == 0) {
#pragma unroll
        for (int g = 0; g < 4; ++g) {
            bias[g] = bih1[g * H + row] + bhh1[g * H + row];
            wxv[g]  = Wih1[g * H + row];
        }
    } else if (wave == 1) {
#pragma unroll
        for (int g = 0; g < 4; ++g)
            bias[g] = bih2[g * H + row] + bhh2[g * H + row];
    }
    const float wlin = (lane < H) ? Wlin[lane] : 0.0f;
    const float bl   = blin[0];

    // ---- pipeline state (per-wave meaning) ----
    float h1reg = 0.0f;          // wave0: h1[lane]
    float h2reg = 0.0f;          // wave1: h2[lane]
    float c1 = 0.0f, c2 = 0.0f;
    f4 u2stash = bias;           // wave1: u2(-1) = b2 (h2 init 0)

    __syncthreads();

#pragma unroll 1
    for (int e = 0; e < TSTEPS + 3; ++e) {
        if (wave == 0) {
            // ---- h1(e) = cell1( b1 + wx*x[e] + Whh1.h1(e-1) ) — fully in-wave
            if (e < TSTEPS) {
                const float xv = sh_x[e];
                float z0 = fmaf(wxv[0], xv, bias[0]);
                float z1 = fmaf(wxv[1], xv, bias[1]);
                float z2 = fmaf(wxv[2], xv, bias[2]);
                float z3 = fmaf(wxv[3], xv, bias[3]);
#pragma unroll
                for (int k = 0; k < H; ++k) {
                    const float hk = rlane(h1reg, k);
                    z0 = fmaf(wg0[k], hk, z0);
                    z1 = fmaf(wg1[k], hk, z1);
                    z2 = fmaf(wg2[k], hk, z2);
                    z3 = fmaf(wg3[k], hk, z3);
                }
                const float ig = sigmoidf_fast(z0);
                const float fg = sigmoidf_fast(z1);
                const float gg = tanhf_fast(z2);
                const float og = sigmoidf_fast(z3);
                c1 = fmaf(fg, c1, ig * gg);
                h1reg = (lane < H) ? og * tanhf_fast(c1) : 0.0f;
                sh_h1[e & 1][lane] = h1reg;
            }
        } else if (wave == 2) {
            // ---- z2a(e-1) = Wih2 . h1(e-1) ----
            if (e >= 1 && e <= TSTEPS) {
                const int s = e - 1;
                const float h1v = sh_h1[s & 1][lane];   // written epoch e-1
                float z0 = 0.0f, z1 = 0.0f, z2 = 0.0f, z3 = 0.0f;
#pragma unroll
                for (int k = 0; k < H; ++k) {
                    const float hk = rlane(h1v, k);
                    z0 = fmaf(wg0[k], hk, z0);
                    z1 = fmaf(wg1[k], hk, z1);
                    z2 = fmaf(wg2[k], hk, z2);
                    z3 = fmaf(wg3[k], hk, z3);
                }
                f4 zv; zv[0] = z0; zv[1] = z1; zv[2] = z2; zv[3] = z3;
                sh_z2a[s & 1][lane] = zv;
            }
        } else if (wave == 1) {
            // ---- finish h2(e-2) = cell2( u2(e-2) + z2a(e-2) ) ----
            if (e >= 2 && e <= TSTEPS + 1) {
                const int s = e - 2;
                const f4 za = sh_z2a[s & 1][lane];      // written epoch e-1
                const float z0 = u2stash[0] + za[0];
                const float z1 = u2stash[1] + za[1];
                const float z2 = u2stash[2] + za[2];
                const float z3 = u2stash[3] + za[3];
                const float ig = sigmoidf_fast(z0);
                const float fg = sigmoidf_fast(z1);
                const float gg = tanhf_fast(z2);
                const float og = sigmoidf_fast(z3);
                c2 = fmaf(fg, c2, ig * gg);
                h2reg = (lane < H) ? og * tanhf_fast(c2) : 0.0f;
                sh_h2[s & 1][lane] = h2reg;
            }
            // ---- u2(e-1) = b2 + Whh2 . h2(e-2) — in-wave ----
            if (e >= 1 && e <= TSTEPS) {
                float u0 = bias[0], u1 = bias[1], u2 = bias[2], u3 = bias[3];
#pragma unroll
                for (int k = 0; k < H; ++k) {
                    const float hk = rlane(h2reg, k);
                    u0 = fmaf(wg0[k], hk, u0);
                    u1 = fmaf(wg1[k], hk, u1);
                    u2 = fmaf(wg2[k], hk, u2);
                    u3 = fmaf(wg3[k], hk, u3);
                }
                u2stash[0] = u0; u2stash[1] = u1; u2stash[2] = u2; u2stash[3] = u3;
            }
        } else {
            // ---- wave3: out(e-3) = Wlin . h2(e-3) + blin  (off critical path)
            if (e >= 3) {
                const int s = e - 3;
                const float hv = sh_h2[s & 1][lane];    // written epoch e-1
                float p = hv * wlin;
                p += __shfl_down(p, 32);
                p += __shfl_down(p, 16);
                p += __shfl_down(p, 8);
                p += __shfl_down(p, 4);
                p += __shfl_down(p, 2);
                p += __shfl_down(p, 1);
                if (lane == 0) sh_out[s] = p + bl;
            }
        }
        __syncthreads();
    }

    // ---- bulk coalesced output store ----
    for (int i = tid; i < TSTEPS / 4; i += 256)
        ((f4*)out)[i] = ((const f4*)sh_out)[i];
}

extern "C" void kernel_launch(void* const* d_in, const int* in_sizes, int n_in,
                              void* d_out, int out_size, void* d_ws, size_t ws_size,
                              hipStream_t stream) {
    const float* x    = (const float*)d_in[0];
    const float* Wih1 = (const float*)d_in[1];
    const float* Whh1 = (const float*)d_in[2];
    const float* bih1 = (const float*)d_in[3];
    const float* bhh1 = (const float*)d_in[4];
    const float* Wih2 = (const float*)d_in[5];
    const float* Whh2 = (const float*)d_in[6];
    const float* bih2 = (const float*)d_in[7];
    const float* bhh2 = (const float*)d_in[8];
    const float* Wlin = (const float*)d_in[9];
    const float* blin = (const float*)d_in[10];
    float* out = (float*)d_out;

    lstm2_pipe_kernel<<<1, 256, 0, stream>>>(
        x, Wih1, Whh1, bih1, bhh1, Wih2, Whh2, bih2, bhh2, Wlin, blin, out);
}